// Round 5
// baseline (246.916 us; speedup 1.0000x reference)
//
#include <hip/hip_runtime.h>

// ---- problem constants -----------------------------------------------------
#define IN_DIM   1024
#define OUT_DIM  1024
#define BATCH    4096
#define NC       8        // N_COEFFS
#define NK       12       // N_KNOTS
#define KSPLINE  (IN_DIM * NC)      // 8192
#define KDIM     (KSPLINE + IN_DIM) // 9216
#define EPS      1e-8f

#define NBLK_A   ((IN_DIM / 256) * (BATCH / 16))      // 1024 A-builder blocks
#define NBLK_W   ((OUT_DIM * (KDIM / 4)) / 256)       // 9216 W-builder blocks

// ---- gemm geometry: m201-template port -------------------------------------
// 256x128 tile, BK=64, 8 waves (2M x 4N, wave-tile 128x32), KSPLIT=2.
// Rounds 0-4 post-mortem: t = 7.6c*ds_read + 10.3c*MFMA fits (SUM, not MAX)
// -> zero LDS/MFMA overlap in lockstep schedules. m201's 2-barrier-per-16-MFMA
// phase rhythm + 3-half-tile-deep ring + once-per-K-tile counted vmcnt is the
// HW-verified fix (62% MfmaUtil). This is a faithful port, not a redesign.
#define BM       256
#define BN       128
#define BK       64
#define KSPLIT   2
#define KPS      (KDIM / KSPLIT)               // 4608
#define NKT      (KPS / BK)                    // 72 K-tiles per block
#define NGBLK    ((BATCH / BM) * (OUT_DIM / BN) * KSPLIT)  // 16*8*2 = 256

// LDS row = 64 halfs = 128 B = 8 x 16B chunks. Read chunk ^= row&7 ->
// 64 lanes spread uniformly 8 dwords/bank (the b128 minimum) = conflict-free.
#define SWZ(r)   ((r) & 7)

typedef _Float16 f16x8  __attribute__((ext_vector_type(8)));
typedef float    f32x4  __attribute__((ext_vector_type(4)));

static __device__ __forceinline__ unsigned short f2h_bits(float f) {
  _Float16 h = (_Float16)f;
  return __builtin_bit_cast(unsigned short, h);
}

// async 16B/lane global->LDS copy; LDS dest is wave-uniform base + lane*16
static __device__ __forceinline__ void gl_lds16(const unsigned short* g, unsigned short* l) {
  __builtin_amdgcn_global_load_lds(
      (const __attribute__((address_space(1))) unsigned int*)g,
      (__attribute__((address_space(3))) unsigned int*)l, 16, 0, 0);
}

// ---- kernel 1: fused prep (A path + W path) — UNCHANGED from round 4 -------
__global__ __launch_bounds__(256) void prep_k(const float* __restrict__ x,
                                              const float* __restrict__ coeffs,
                                              const float* __restrict__ bw,
                                              const float* __restrict__ gsl,
                                              const float* __restrict__ gstart,
                                              const float* __restrict__ rsp,
                                              unsigned short* __restrict__ A,
                                              unsigned short* __restrict__ W,
                                              float* __restrict__ out) {
  const int blk = blockIdx.x;
  if (blk < NBLK_A) {
    const int i  = (blk & 3) * 256 + threadIdx.x;
    const int b0 = (blk >> 2) * 16;
    const float rs = rsp[0];
    float g[NK];
    float acc = gstart[i];
    g[0] = acc;
#pragma unroll
    for (int t = 0; t < NK - 1; ++t) {
      float v  = gsl[i * (NK - 1) + t];
      float sp = (v > 20.f) ? v : log1pf(expf(v));  // softplus
      acc += sp;
      g[t + 1] = acc;
    }
    float r[30];
#pragma unroll
    for (int j = 0; j < 11; ++j) r[j]      = 1.f / (g[j + 1] - g[j] + EPS);
#pragma unroll
    for (int j = 0; j < 10; ++j) r[11 + j] = 1.f / (g[j + 2] - g[j] + EPS);
#pragma unroll
    for (int j = 0; j <  9; ++j) r[21 + j] = 1.f / (g[j + 3] - g[j] + EPS);

#pragma unroll 4
    for (int bb = 0; bb < 16; ++bb) {
      const int b = b0 + bb;
      float xv = x[(size_t)b * IN_DIM + i];
      float bas[NK - 1];
#pragma unroll
      for (int k = 0; k < NK - 1; ++k)
        bas[k] = (xv >= g[k] && xv < g[k + 1]) ? 1.f : 0.f;
      const int off[3] = {0, 11, 21};
#pragma unroll
      for (int d = 1; d <= 3; ++d) {
#pragma unroll
        for (int k = 0; k < NK - 1 - d; ++k) {
          float left  = (xv - g[k])         * r[off[d - 1] + k];
          float right = (g[k + d + 1] - xv) * r[off[d - 1] + k + 1];
          bas[k] = left * bas[k] + right * bas[k + 1];
        }
      }
      uint4 pack;
      pack.x = (unsigned)f2h_bits(bas[0]) | ((unsigned)f2h_bits(bas[1]) << 16);
      pack.y = (unsigned)f2h_bits(bas[2]) | ((unsigned)f2h_bits(bas[3]) << 16);
      pack.z = (unsigned)f2h_bits(bas[4]) | ((unsigned)f2h_bits(bas[5]) << 16);
      pack.w = (unsigned)f2h_bits(bas[6]) | ((unsigned)f2h_bits(bas[7]) << 16);
      *(uint4*)&A[(size_t)b * KDIM + i * NC] = pack;
      float s = xv / (1.f + expf(-xv));  // silu
      A[(size_t)b * KDIM + KSPLINE + i] = f2h_bits(s);
      out[(size_t)b * OUT_DIM + i] = rs * xv;  // init for gemm's += epilogue
    }
  } else {
    int idx = (blk - NBLK_A) * 256 + threadIdx.x;
    int n  = idx / (KDIM / 4);
    int k4 = (idx - n * (KDIM / 4)) * 4;
    float4 v;
    if (k4 < KSPLINE) v = *(const float4*)&coeffs[(size_t)n * KSPLINE + k4];
    else              v = *(const float4*)&bw[(size_t)n * IN_DIM + (k4 - KSPLINE)];
    ushort4 o;
    o.x = f2h_bits(v.x); o.y = f2h_bits(v.y); o.z = f2h_bits(v.z); o.w = f2h_bits(v.w);
    *(ushort4*)&W[(size_t)n * KDIM + k4] = o;
  }
}

// ---- kernel 2: out/P += A @ W^T — m201-style 2-phase/K-tile pipeline -------
// LDS: A-ring 6 half-slots (128x64h = 16 KB) + B-ring 6 (64x64h = 8 KB) = 144 KB.
// Half-tile (tile u, half h, operand X) lives in X-ring slot (2u+h) % 6; its
// previous occupant is tile u-2's half h, whose reads retired before tile u-1
// ended -> staging tile u+2 during tile u is hazard-free by construction
// (3 half-tiles in flight, the template's depth).
// Per-thread load FIFO: 6 loads/tile (A0,A0',B0 | A1,A1',B1); prologue 12
// (tiles 0,1); vmcnt(6) at each tile's phase-1 end retires tile u+1 exactly.
// Phase = {ds_read frags | stage 3 | barrier | lgkmcnt(0) | 16 MFMA | barrier}.
__global__ __launch_bounds__(512, 1) void gemm_k(const unsigned short* __restrict__ A,
                                                 const unsigned short* __restrict__ W,
                                                 float* __restrict__ out,
                                                 float* __restrict__ P,
                                                 int use_partial) {
  __shared__ __align__(16) unsigned short Al[6][128][64];  // 96 KB
  __shared__ __align__(16) unsigned short Bl[6][64][64];   // 48 KB
  const int tid  = threadIdx.x;
  const int wave = tid >> 6;
  const int lane = tid & 63;

  // T1: XCD decode (256 % 8 == 0 -> bijective). Each XCD: 1 ks x 2 bn x 16 bm
  // -> W-slice 2 x 128 x 4608 x 2B = 2.36 MB, L2-resident per XCD.
  const int s  = (blockIdx.x & 7) * 32 + (blockIdx.x >> 3);
  const int ks = s >> 7;                     // 0..1
  const int bn = (s >> 4) & 7;               // 0..7
  const int bm = s & 15;                     // 0..15

  // staging map: thread t -> row t>>3 (of 64 per call), 16B chunk t&7; source
  // chunk pre-XOR'd by the read-side involution (rule #21). SWZ(r+64)==SWZ(r)
  // and SWZ(r+128)==SWZ(r), so one swizzled base serves all half offsets.
  const int srow = tid >> 3;                 // 0..63
  const int scsw = ((tid & 7) ^ SWZ(srow)) * 8;
  const unsigned short* aG = A + (size_t)(bm * BM + srow) * KDIM + (size_t)ks * KPS + scsw;
  const unsigned short* bG = W + (size_t)(bn * BN + srow) * KDIM + (size_t)ks * KPS + scsw;

  // A-half h of tile u -> slot sl (2 calls: rows 0-63, 64-127 of the half)
#define STAGE_A(u, sl, h) do {                                                 \
    const size_t k_ = (size_t)(u) * BK;                                        \
    gl_lds16(aG + ((size_t)(h) * 128)      * KDIM + k_, &Al[sl][wave * 8][0]); \
    gl_lds16(aG + ((size_t)(h) * 128 + 64) * KDIM + k_, &Al[sl][64 + wave * 8][0]); \
  } while (0)
#define STAGE_B(u, sl, h)                                                      \
    gl_lds16(bG + ((size_t)(h) * 64) * KDIM + (size_t)(u) * BK, &Bl[sl][wave * 8][0])

  // fragment map (16x16x32): row = lane&15, k-chunk kg = lane>>4 (8 halfs);
  // K=64 row -> chunk index ch = kc*4+kg, read at (ch ^ SWZ(row))*8 halfs.
  const int l15 = lane & 15;
  const int kg  = lane >> 4;
  const int wm  = (wave >> 2) * 128;    // 2 M-wave groups (= A half index)
  const int hA  = wave >> 2;
  const int hB  = (wave & 3) >> 1;      // B half index
  const int wnl = (wave & 1) * 32;      // B row-in-half base

  f32x4 acc[8][2] = {};
  f16x8 af[4][2], bf[2][2];

  auto LDA = [&](const unsigned short (*As_)[64], int qm) {
#pragma unroll
    for (int i = 0; i < 4; ++i) {
      const int rh = qm * 64 + i * 16 + l15;
      const int sw = SWZ(rh);
#pragma unroll
      for (int kc = 0; kc < 2; ++kc)
        af[i][kc] = *(const f16x8*)&As_[rh][((kc * 4 + kg) ^ sw) * 8];
    }
  };
  auto LDB = [&](const unsigned short (*Bs_)[64]) {
#pragma unroll
    for (int j = 0; j < 2; ++j) {
      const int rh = wnl + j * 16 + l15;
      const int sw = SWZ(rh);
#pragma unroll
      for (int kc = 0; kc < 2; ++kc)
        bf[j][kc] = *(const f16x8*)&Bs_[rh][((kc * 4 + kg) ^ sw) * 8];
    }
  };
  auto MFMA_Q = [&](int m0) {
#pragma unroll
    for (int kc = 0; kc < 2; ++kc)
#pragma unroll
      for (int i = 0; i < 4; ++i)
#pragma unroll
        for (int j = 0; j < 2; ++j)
          acc[m0 + i][j] = __builtin_amdgcn_mfma_f32_16x16x32_f16(af[i][kc], bf[j][kc], acc[m0 + i][j], 0, 0, 0);
  };

  // prologue: tiles 0 (slots 0,1) and 1 (slots 2,3) staged in per-tile FIFO
  // order [A,A,B | A,A,B]; vmcnt(6) -> this thread's tile-0 loads retired;
  // barrier publishes all waves' tile-0 stages.
  STAGE_A(0, 0, 0); STAGE_B(0, 0, 0); STAGE_A(0, 1, 1); STAGE_B(0, 1, 1);
  STAGE_A(1, 2, 0); STAGE_B(1, 2, 0); STAGE_A(1, 3, 1); STAGE_B(1, 3, 1);
  asm volatile("s_waitcnt vmcnt(6)" ::: "memory");
  __builtin_amdgcn_s_barrier();

#define TILE(u, S0) do {                                                       \
    const unsigned short (*As_)[64] = Al[(S0) + hA];                           \
    const unsigned short (*Bs_)[64] = Bl[(S0) + hB];                           \
    /* ---- phase 0: quadrant mt0-3, stage (u+2).{A0,B0} ---- */               \
    LDA(As_, 0); LDB(Bs_);                                                     \
    if ((u) + 2 < NKT) { STAGE_A((u) + 2, ((S0) + 4) % 6, 0);                  \
                         STAGE_B((u) + 2, ((S0) + 4) % 6, 0); }                \
    __builtin_amdgcn_s_barrier();                                              \
    asm volatile("s_waitcnt lgkmcnt(0)" ::: "memory");                         \
    __builtin_amdgcn_sched_barrier(0);                                         \
    __builtin_amdgcn_s_setprio(1);                                             \
    MFMA_Q(0);                                                                 \
    __builtin_amdgcn_s_setprio(0);                                             \
    __builtin_amdgcn_s_barrier();                                              \
    /* ---- phase 1: quadrant mt4-7 (bf reused), stage (u+2).{A1,B1} ---- */   \
    LDA(As_, 1);                                                               \
    if ((u) + 2 < NKT) { STAGE_A((u) + 2, ((S0) + 5) % 6, 1);                  \
                         STAGE_B((u) + 2, ((S0) + 5) % 6, 1); }                \
    __builtin_amdgcn_s_barrier();                                              \
    asm volatile("s_waitcnt lgkmcnt(0)" ::: "memory");                         \
    __builtin_amdgcn_sched_barrier(0);                                         \
    __builtin_amdgcn_s_setprio(1);                                             \
    MFMA_Q(4);                                                                 \
    __builtin_amdgcn_s_setprio(0);                                             \
    /* counted vmcnt: tile u+1 resident for all waves after the barrier */     \
    if ((u) < NKT - 2)       asm volatile("s_waitcnt vmcnt(6)" ::: "memory");  \
    else if ((u) == NKT - 2) asm volatile("s_waitcnt vmcnt(0)" ::: "memory");  \
    if ((u) < NKT - 1) __builtin_amdgcn_s_barrier();                           \
  } while (0)

  // slot base (2u)%6 cycles with period 3 -> unroll by 3 keeps slots constant
  for (int uu = 0; uu < NKT; uu += 3) {
    TILE(uu + 0, 0);
    TILE(uu + 1, 2);
    TILE(uu + 2, 4);
  }
#undef TILE
#undef STAGE_A
#undef STAGE_B

  // epilogue: C/D 16x16 layout col=lane&15, row=(lane>>4)*4+reg (m89-verified)
#pragma unroll
  for (int mt = 0; mt < 8; ++mt) {
#pragma unroll
    for (int reg = 0; reg < 4; ++reg) {
      const int row = bm * BM + wm + mt * 16 + kg * 4 + reg;
      const size_t ro = (size_t)row * OUT_DIM;
#pragma unroll
      for (int nt = 0; nt < 2; ++nt) {
        const int col = bn * BN + (wave & 3) * 32 + nt * 16 + l15;
        const float v = acc[mt][nt][reg];
        if (use_partial) {
          if (ks == 0) out[ro + col] += v;   // exclusive owner of slice 0
          else         P[ro + col]    = v;   // plain store, folded by reduce_k
        } else {
          atomicAdd(&out[ro + col], v);      // ws-too-small fallback
        }
      }
    }
  }
}

// ---- kernel 3: out += P (K-split fold) -------------------------------------
__global__ __launch_bounds__(256) void reduce_k(float* __restrict__ out,
                                                const float* __restrict__ P) {
  const int n4 = (BATCH * OUT_DIM) / 4;      // 1,048,576 float4s
  for (int i = blockIdx.x * 256 + threadIdx.x; i < n4; i += gridDim.x * 256) {
    float4 o = ((const float4*)out)[i];
    float4 p = ((const float4*)P)[i];
    o.x += p.x; o.y += p.y; o.z += p.z; o.w += p.w;
    ((float4*)out)[i] = o;
  }
}

// ---- host-side launch ------------------------------------------------------
extern "C" void kernel_launch(void* const* d_in, const int* in_sizes, int n_in,
                              void* d_out, int out_size, void* d_ws, size_t ws_size,
                              hipStream_t stream) {
  const float* x      = (const float*)d_in[0];  // (4096, 1024) fp32
  const float* coeffs = (const float*)d_in[1];  // (1024, 8192)
  const float* bw     = (const float*)d_in[2];  // (1024, 1024)
  const float* gsl    = (const float*)d_in[3];  // (1024, 11)
  const float* gstart = (const float*)d_in[4];  // (1024, 1)
  const float* rsp    = (const float*)d_in[5];  // (1,)

  // ws layout: A (75.5 MB f16) | W (18.9 MB f16) | P (16.8 MB f32) = 111.2 MB
  // (identical to round-4's proven-fit layout)
  const size_t szA = (size_t)BATCH * KDIM * 2;
  const size_t szW = (size_t)OUT_DIM * KDIM * 2;
  const size_t szP = (size_t)BATCH * OUT_DIM * 4;
  char* ws = (char*)d_ws;
  unsigned short* A  = (unsigned short*)ws;
  unsigned short* W  = (unsigned short*)(ws + szA);
  float*          P  = (float*)(ws + szA + szW);
  float*          out = (float*)d_out;
  const int use_partial = (ws_size >= szA + szW + szP) ? 1 : 0;

  prep_k<<<NBLK_A + NBLK_W, 256, 0, stream>>>(x, coeffs, bw, gsl, gstart, rsp, A, W, out);
  gemm_k<<<NGBLK, 512, 0, stream>>>(A, W, out, P, use_partial);
  if (use_partial) reduce_k<<<2048, 256, 0, stream>>>(out, P);
}